// Round 5
// baseline (1411.128 us; speedup 1.0000x reference)
//
#include <hip/hip_runtime.h>
#include <hip/hip_fp16.h>

typedef _Float16 f16;
typedef __attribute__((ext_vector_type(8))) _Float16 f16x8;
typedef __attribute__((ext_vector_type(4))) _Float16 f16x4;
typedef __attribute__((ext_vector_type(4))) float f32x4;
typedef __attribute__((ext_vector_type(4))) float float4v;

// Shapes: x[512,256,256], carry0[256,256], Wi[256,768], bi[768],
//         Wh[256,768], bhn[256], Wo[256,16], bo[16] -> out[512,256,16] f32
//
// gx workspace layout (scan-fragment order), f16:
//   vecidx = ((t*16 + blk)*8 + wave)*6 + (gate*2 + nt)
//   element = vecidx*256 + lane*4 + j   (j = acc reg index = row&3)

static __device__ __forceinline__ float sigm(float x) {
  return __builtin_amdgcn_rcpf(1.0f + __expf(-x));
}
static __device__ __forceinline__ float tanh_fast(float x) {
  float e = __expf(2.0f * x);
  return 1.0f - 2.0f * __builtin_amdgcn_rcpf(e + 1.0f);
}

// ---------------- K0: transpose+convert Wi -> WiT[768][256] f16 -------------
__global__ void k_prep_wit(const float* __restrict__ Wi, f16* __restrict__ WiT) {
  int n = blockIdx.x;   // 0..767
  int k = threadIdx.x;  // 0..255
  WiT[n * 256 + k] = (f16)Wi[(size_t)k * 768 + n];
}

// ---------------- K1: gx = x @ Wi + bi  (fp16 MFMA, 128x128 tile) -----------
__global__ __launch_bounds__(256, 4) void k_gemm_gx(
    const float* __restrict__ x, const f16* __restrict__ WiT,
    const float* __restrict__ bi, f16* __restrict__ gx) {
  __shared__ f16 As[128 * 64];  // [row][k] fp16, XOR-swizzled
  __shared__ f16 Bs[128 * 64];  // [n][k]  fp16 (B transposed), XOR-swizzled
  const int tid = threadIdx.x;
  const int lane = tid & 63;
  const int wave = tid >> 6;
  const int wm = wave >> 1, wn = wave & 1;
  const int m0 = blockIdx.y * 128;
  const int n0 = blockIdx.x * 128;

  f32x4 acc[4][4] = {};

  for (int ks = 0; ks < 4; ++ks) {
    const int k0 = ks * 64;
#pragma unroll
    for (int i = 0; i < 8; ++i) {
      int c = i * 256 + tid;
      int row = c >> 4, cx = c & 15;
      float4v v = *reinterpret_cast<const float4v*>(
          x + (size_t)(m0 + row) * 256 + k0 + cx * 4);
      f16x4 hv;
      hv[0] = (f16)v[0]; hv[1] = (f16)v[1]; hv[2] = (f16)v[2]; hv[3] = (f16)v[3];
      int boff = row * 128 + ((cx * 8) ^ ((row & 7) << 4));
      *reinterpret_cast<f16x4*>(reinterpret_cast<char*>(As) + boff) = hv;
    }
#pragma unroll
    for (int i = 0; i < 4; ++i) {
      int c = i * 256 + tid;
      int n = c >> 3, cx = c & 7;
      f16x8 v = *reinterpret_cast<const f16x8*>(
          WiT + (size_t)(n0 + n) * 256 + k0 + cx * 8);
      int boff = n * 128 + ((cx * 16) ^ ((n & 7) << 4));
      *reinterpret_cast<f16x8*>(reinterpret_cast<char*>(Bs) + boff) = v;
    }
    __syncthreads();
#pragma unroll
    for (int kt = 0; kt < 2; ++kt) {
      const int kb = kt * 64 + ((lane >> 4) << 4);
      f16x8 a[4], b[4];
#pragma unroll
      for (int mt = 0; mt < 4; ++mt) {
        int r = wm * 64 + mt * 16 + (lane & 15);
        a[mt] = *reinterpret_cast<const f16x8*>(
            reinterpret_cast<const char*>(As) + r * 128 + (kb ^ ((r & 7) << 4)));
      }
#pragma unroll
      for (int nt = 0; nt < 4; ++nt) {
        int r = wn * 64 + nt * 16 + (lane & 15);
        b[nt] = *reinterpret_cast<const f16x8*>(
            reinterpret_cast<const char*>(Bs) + r * 128 + (kb ^ ((r & 7) << 4)));
      }
#pragma unroll
      for (int mt = 0; mt < 4; ++mt)
#pragma unroll
        for (int nt = 0; nt < 4; ++nt)
          acc[mt][nt] = __builtin_amdgcn_mfma_f32_16x16x32_f16(
              a[mt], b[nt], acc[mt][nt], 0, 0, 0);
    }
    __syncthreads();
  }
  // epilogue: + bi, cvt f16, scatter-store in scan-fragment layout (8B stores)
  const int t_  = blockIdx.y >> 1;
  const int bhf = blockIdx.y & 1;
  const int gg  = blockIdx.x >> 1;
  const int xh  = blockIdx.x & 1;
  float biv[4];
#pragma unroll
  for (int nt = 0; nt < 4; ++nt) biv[nt] = bi[n0 + wn * 64 + nt * 16 + (lane & 15)];
#pragma unroll
  for (int mt = 0; mt < 4; ++mt) {
    const int blk = bhf * 8 + wm * 4 + mt;
#pragma unroll
    for (int nt = 0; nt < 4; ++nt) {
      const int w = xh * 4 + wn * 2 + (nt >> 1);
      const int vecidx = ((t_ * 16 + blk) * 8 + w) * 6 + gg * 2 + (nt & 1);
      f16x4 hv;
#pragma unroll
      for (int r = 0; r < 4; ++r) hv[r] = (f16)(acc[mt][nt][r] + biv[nt]);
      *reinterpret_cast<f16x4*>(gx + (size_t)vecidx * 256 + lane * 4) = hv;
    }
  }
}

// ---------------- K2: GRU scan + fused head, 16 blocks x 8 waves ------------
// ALL Wh gate weights live in VGPRs (192 regs). h kept as MFMA A-frags in
// LDS (double buffer, granule swizzle p = g^(g>>3), conflict-free). gx
// prefetched one step ahead into a register double buffer (t unrolled by 2).
// acc C-initialized from gx (r,z) / bhn (n). Lightweight barrier: only
// lgkmcnt drained (out-stores and gx prefetch stay in flight).
__global__ __launch_bounds__(512) void k_scan(
    const float* __restrict__ carry0, const float* __restrict__ Wh,
    const float* __restrict__ bhn, const f16* __restrict__ gxL,
    const float* __restrict__ Wo, const float* __restrict__ bo,
    float* __restrict__ out) {
  __shared__ f16 ha[2 * 8 * 64 * 8];  // 16384 B: h A-frag double buffer
  __shared__ f16 wofs[8 * 64 * 8];    // 8192 B: Wo B-frags
  const int tid = threadIdx.x;
  const int lane = tid & 63;
  const int wave = tid >> 6;  // 0..7
  const int l15 = lane & 15, l4 = lane >> 4;
  const int r0 = blockIdx.x * 16;

  // All 3 Wh gates -> register fragments (B[k][j]: j=lane&15,
  // k = kt*32 + (lane>>4)*8 + e).  192 VGPRs.
  f16x8 whf[3][2][8];
#pragma unroll
  for (int g = 0; g < 3; ++g)
#pragma unroll
    for (int nt = 0; nt < 2; ++nt) {
      const int col = g * 256 + wave * 32 + nt * 16 + l15;
#pragma unroll
      for (int kt = 0; kt < 8; ++kt)
#pragma unroll
        for (int e = 0; e < 8; ++e)
          whf[g][nt][kt][e] = (f16)Wh[(size_t)(kt * 32 + l4 * 8 + e) * 768 + col];
    }
  // Wo -> LDS B-frags; wave w writes frame kt=w
  {
    f16x8 v;
#pragma unroll
    for (int e = 0; e < 8; ++e)
      v[e] = (f16)Wo[(wave * 32 + l4 * 8 + e) * 16 + l15];
    *reinterpret_cast<f16x8*>(reinterpret_cast<char*>(wofs) + wave * 1024 +
                              lane * 16) = v;
  }
  float bh[2];
#pragma unroll
  for (int nt = 0; nt < 2; ++nt) bh[nt] = bhn[wave * 32 + nt * 16 + l15];
  const float bov = bo[l15];

  // init h_0: registers (C-layout ownership) + A-frags in buffer 0
  float hcur[2][4];
#pragma unroll
  for (int nt = 0; nt < 2; ++nt) {
    const int s = nt * 2 + (l15 >> 3);
#pragma unroll
    for (int j = 0; j < 4; ++j) {
      const int r = l4 * 4 + j;
      const int c = wave * 32 + nt * 16 + l15;
      float h = carry0[(size_t)(r0 + r) * 256 + c];
      hcur[nt][j] = h;
      const int gl = s * 16 + r;
      const int p = gl ^ (gl >> 3);
      *reinterpret_cast<f16*>(reinterpret_cast<char*>(ha) + wave * 1024 + p * 16 +
                              (l15 & 7) * 2) = (f16)h;
    }
  }
  __syncthreads();

  const f16* gp0 = gxL + ((size_t)blockIdx.x * 8 + wave) * 1536 + lane * 4;
  const int rdoff = (lane ^ (lane >> 3)) * 16;  // swizzled A-frag read offset

  f16x4 gva[6], gvb[6];
#pragma unroll
  for (int i = 0; i < 6; ++i)
    gva[i] = *reinterpret_cast<const f16x4*>(gp0 + i * 256);

  auto step = [&](int cur, int nxt, f16x4 (&gv)[6], f16x4 (&gvn)[6],
                  const f16* gpn, int tt) {
    // prefetch NEXT step's gx (full step of latency cover)
#pragma unroll
    for (int i = 0; i < 6; ++i)
      gvn[i] = *reinterpret_cast<const f16x4*>(gpn + i * 256);

    // C-init: r,z from gx; n from bhn
    f32x4 acc[3][2];
#pragma unroll
    for (int nt = 0; nt < 2; ++nt)
#pragma unroll
      for (int j = 0; j < 4; ++j) {
        acc[0][nt][j] = (float)gv[nt][j];
        acc[1][nt][j] = (float)gv[2 + nt][j];
        acc[2][nt][j] = bh[nt];
      }
#pragma unroll
    for (int kt = 0; kt < 8; ++kt) {
      f16x8 a = *reinterpret_cast<const f16x8*>(
          reinterpret_cast<const char*>(ha) + cur + kt * 1024 + rdoff);
#pragma unroll
      for (int nt = 0; nt < 2; ++nt) {
        acc[0][nt] = __builtin_amdgcn_mfma_f32_16x16x32_f16(a, whf[0][nt][kt],
                                                            acc[0][nt], 0, 0, 0);
        acc[1][nt] = __builtin_amdgcn_mfma_f32_16x16x32_f16(a, whf[1][nt][kt],
                                                            acc[1][nt], 0, 0, 0);
        acc[2][nt] = __builtin_amdgcn_mfma_f32_16x16x32_f16(a, whf[2][nt][kt],
                                                            acc[2][nt], 0, 0, 0);
      }
    }
    // elementwise GRU + write h_{t+1} A-frags into next buffer
#pragma unroll
    for (int nt = 0; nt < 2; ++nt) {
      const int s = nt * 2 + (l15 >> 3);
#pragma unroll
      for (int j = 0; j < 4; ++j) {
        const int r = l4 * 4 + j;
        float rg = sigm(acc[0][nt][j]);
        float zg = sigm(acc[1][nt][j]);
        float ng = tanh_fast((float)gv[4 + nt][j] + rg * acc[2][nt][j]);
        float h = ng + zg * (hcur[nt][j] - ng);
        hcur[nt][j] = h;
        const int gl = s * 16 + r;
        const int p = gl ^ (gl >> 3);
        *reinterpret_cast<f16*>(reinterpret_cast<char*>(ha) + nxt + wave * 1024 +
                                p * 16 + (l15 & 7) * 2) = (f16)h;
      }
    }
    // fused head on wave 0 (after elementwise: reuses freed acc registers)
    if (wave == 0) {
      f32x4 aco = {};
#pragma unroll
      for (int kt = 0; kt < 8; ++kt) {
        f16x8 a = *reinterpret_cast<const f16x8*>(
            reinterpret_cast<const char*>(ha) + cur + kt * 1024 + rdoff);
        f16x8 wb = *reinterpret_cast<const f16x8*>(
            reinterpret_cast<const char*>(wofs) + kt * 1024 + lane * 16);
        aco = __builtin_amdgcn_mfma_f32_16x16x32_f16(a, wb, aco, 0, 0, 0);
      }
      if (tt > 0) {
#pragma unroll
        for (int r = 0; r < 4; ++r) {
          float y = aco[r] + bov;
          if (l15 >= 8) y = __expf(fminf(fmaxf(y, -20.0f), 2.0f));
          out[((size_t)(tt - 1) * 256 + r0 + l4 * 4 + r) * 16 + l15] = y;
        }
      }
    }
    // lightweight barrier: order LDS h-handoff only (no vmcnt drain)
    asm volatile("s_waitcnt lgkmcnt(0)\n\ts_barrier" ::: "memory");
  };

  for (int t = 0; t < 512; t += 2) {
    const f16* gp1 = gp0 + (size_t)(t + 1) * 196608;
    const f16* gp2 = gp0 + (size_t)(t + 2 <= 511 ? t + 2 : 511) * 196608;
    step(0, 8192, gva, gvb, gp1, t);
    step(8192, 0, gvb, gva, gp2, t + 1);
  }

  // final head: out[511] = h_512 @ Wo  (h_512 lives in buffer 0)
  if (wave == 0) {
    f32x4 aco = {};
#pragma unroll
    for (int kt = 0; kt < 8; ++kt) {
      f16x8 a = *reinterpret_cast<const f16x8*>(
          reinterpret_cast<const char*>(ha) + kt * 1024 + rdoff);
      f16x8 wb = *reinterpret_cast<const f16x8*>(
          reinterpret_cast<const char*>(wofs) + kt * 1024 + lane * 16);
      aco = __builtin_amdgcn_mfma_f32_16x16x32_f16(a, wb, aco, 0, 0, 0);
    }
#pragma unroll
    for (int r = 0; r < 4; ++r) {
      float y = aco[r] + bov;
      if (l15 >= 8) y = __expf(fminf(fmaxf(y, -20.0f), 2.0f));
      out[((size_t)511 * 256 + r0 + l4 * 4 + r) * 16 + l15] = y;
    }
  }
}

extern "C" void kernel_launch(void* const* d_in, const int* in_sizes, int n_in,
                              void* d_out, int out_size, void* d_ws, size_t ws_size,
                              hipStream_t stream) {
  const float* x      = (const float*)d_in[0];
  const float* carry0 = (const float*)d_in[1];
  const float* Wi     = (const float*)d_in[2];
  const float* bi     = (const float*)d_in[3];
  const float* Wh     = (const float*)d_in[4];
  const float* bhn    = (const float*)d_in[5];
  const float* Wo     = (const float*)d_in[6];
  const float* bo     = (const float*)d_in[7];
  float* out = (float*)d_out;

  f16* gx  = (f16*)d_ws;                       // 512*256*768 f16 = 192 MiB
  f16* WiT = gx + (size_t)512 * 256 * 768;     // 768*256 f16

  k_prep_wit<<<dim3(768), dim3(256), 0, stream>>>(Wi, WiT);
  k_gemm_gx<<<dim3(6, 1024), dim3(256), 0, stream>>>(x, WiT, bi, gx);
  k_scan<<<dim3(16), dim3(512), 0, stream>>>(carry0, Wh, bhn, gx, Wo, bo, out);
}

// Round 6
// 1222.204 us; speedup vs baseline: 1.1546x; 1.1546x over previous
//
#include <hip/hip_runtime.h>
#include <hip/hip_fp16.h>

typedef _Float16 f16;
typedef __attribute__((ext_vector_type(8))) _Float16 f16x8;
typedef __attribute__((ext_vector_type(4))) _Float16 f16x4;
typedef __attribute__((ext_vector_type(4))) float f32x4;
typedef __attribute__((ext_vector_type(4))) float float4v;

// Shapes: x[512,256,256], carry0[256,256], Wi[256,768], bi[768],
//         Wh[256,768], bhn[256], Wo[256,16], bo[16] -> out[512,256,16] f32
//
// gx workspace layout (scan-fragment order), f16:
//   vecidx = ((t*16 + blk)*8 + wave)*6 + (gate*2 + nt)
//   element = vecidx*256 + lane*4 + j   (j = acc reg index = row&3)

static __device__ __forceinline__ float sigm(float x) {
  return __builtin_amdgcn_rcpf(1.0f + __expf(-x));
}
static __device__ __forceinline__ float tanh_fast(float x) {
  float e = __expf(2.0f * x);
  return 1.0f - 2.0f * __builtin_amdgcn_rcpf(e + 1.0f);
}

// ---------------- K0: transpose+convert Wi -> WiT[768][256] f16 -------------
__global__ void k_prep_wit(const float* __restrict__ Wi, f16* __restrict__ WiT) {
  int n = blockIdx.x;   // 0..767
  int k = threadIdx.x;  // 0..255
  WiT[n * 256 + k] = (f16)Wi[(size_t)k * 768 + n];
}

// ---------------- K1: gx = x @ Wi + bi  (fp16 MFMA, 128x128 tile) -----------
__global__ __launch_bounds__(256, 4) void k_gemm_gx(
    const float* __restrict__ x, const f16* __restrict__ WiT,
    const float* __restrict__ bi, f16* __restrict__ gx) {
  __shared__ f16 As[128 * 64];  // [row][k] fp16, XOR-swizzled
  __shared__ f16 Bs[128 * 64];  // [n][k]  fp16 (B transposed), XOR-swizzled
  const int tid = threadIdx.x;
  const int lane = tid & 63;
  const int wave = tid >> 6;
  const int wm = wave >> 1, wn = wave & 1;
  const int m0 = blockIdx.y * 128;
  const int n0 = blockIdx.x * 128;

  f32x4 acc[4][4] = {};

  for (int ks = 0; ks < 4; ++ks) {
    const int k0 = ks * 64;
#pragma unroll
    for (int i = 0; i < 8; ++i) {
      int c = i * 256 + tid;
      int row = c >> 4, cx = c & 15;
      float4v v = *reinterpret_cast<const float4v*>(
          x + (size_t)(m0 + row) * 256 + k0 + cx * 4);
      f16x4 hv;
      hv[0] = (f16)v[0]; hv[1] = (f16)v[1]; hv[2] = (f16)v[2]; hv[3] = (f16)v[3];
      int boff = row * 128 + ((cx * 8) ^ ((row & 7) << 4));
      *reinterpret_cast<f16x4*>(reinterpret_cast<char*>(As) + boff) = hv;
    }
#pragma unroll
    for (int i = 0; i < 4; ++i) {
      int c = i * 256 + tid;
      int n = c >> 3, cx = c & 7;
      f16x8 v = *reinterpret_cast<const f16x8*>(
          WiT + (size_t)(n0 + n) * 256 + k0 + cx * 8);
      int boff = n * 128 + ((cx * 16) ^ ((n & 7) << 4));
      *reinterpret_cast<f16x8*>(reinterpret_cast<char*>(Bs) + boff) = v;
    }
    __syncthreads();
#pragma unroll
    for (int kt = 0; kt < 2; ++kt) {
      const int kb = kt * 64 + ((lane >> 4) << 4);
      f16x8 a[4], b[4];
#pragma unroll
      for (int mt = 0; mt < 4; ++mt) {
        int r = wm * 64 + mt * 16 + (lane & 15);
        a[mt] = *reinterpret_cast<const f16x8*>(
            reinterpret_cast<const char*>(As) + r * 128 + (kb ^ ((r & 7) << 4)));
      }
#pragma unroll
      for (int nt = 0; nt < 4; ++nt) {
        int r = wn * 64 + nt * 16 + (lane & 15);
        b[nt] = *reinterpret_cast<const f16x8*>(
            reinterpret_cast<const char*>(Bs) + r * 128 + (kb ^ ((r & 7) << 4)));
      }
#pragma unroll
      for (int mt = 0; mt < 4; ++mt)
#pragma unroll
        for (int nt = 0; nt < 4; ++nt)
          acc[mt][nt] = __builtin_amdgcn_mfma_f32_16x16x32_f16(
              a[mt], b[nt], acc[mt][nt], 0, 0, 0);
    }
    __syncthreads();
  }
  // epilogue: + bi, cvt f16, scatter-store in scan-fragment layout (8B stores)
  const int t_  = blockIdx.y >> 1;
  const int bhf = blockIdx.y & 1;
  const int gg  = blockIdx.x >> 1;
  const int xh  = blockIdx.x & 1;
  float biv[4];
#pragma unroll
  for (int nt = 0; nt < 4; ++nt) biv[nt] = bi[n0 + wn * 64 + nt * 16 + (lane & 15)];
#pragma unroll
  for (int mt = 0; mt < 4; ++mt) {
    const int blk = bhf * 8 + wm * 4 + mt;
#pragma unroll
    for (int nt = 0; nt < 4; ++nt) {
      const int w = xh * 4 + wn * 2 + (nt >> 1);
      const int vecidx = ((t_ * 16 + blk) * 8 + w) * 6 + gg * 2 + (nt & 1);
      f16x4 hv;
#pragma unroll
      for (int r = 0; r < 4; ++r) hv[r] = (f16)(acc[mt][nt][r] + biv[nt]);
      *reinterpret_cast<f16x4*>(gx + (size_t)vecidx * 256 + lane * 4) = hv;
    }
  }
}

// ---------------- K2: GRU scan + fused head, 16 blocks x 8 waves ------------
// R4 structure (n-gate weights in LDS, r/z in 128 VGPRs -- fits the 256-reg
// unified budget at 2 waves/SIMD; R5's 192-reg whf spilled to scratch).
// Changes vs R4: (a) lightweight barrier (lgkmcnt only -- no vmcnt drain, gx
// prefetch + out stores stay in flight across the barrier), (b) MFMA C-init
// from gx (r,z) / bhn (n) removes the post-MFMA adds, (c) unroll-by-2.
__global__ __launch_bounds__(512, 2) void k_scan(
    const float* __restrict__ carry0, const float* __restrict__ Wh,
    const float* __restrict__ bhn, const f16* __restrict__ gxL,
    const float* __restrict__ Wo, const float* __restrict__ bo,
    float* __restrict__ out) {
  __shared__ f16 nfr[8 * 2 * 8 * 64 * 8];  // 131072 B: n-gate B-frags
  __shared__ f16 ha[2 * 8 * 64 * 8];       // 16384 B: h A-frag double buffer
  __shared__ f16 wofs[8 * 64 * 8];         // 8192 B: Wo B-frags
  const int tid = threadIdx.x;
  const int lane = tid & 63;
  const int wave = tid >> 6;  // 0..7
  const int l15 = lane & 15, l4 = lane >> 4;
  const int r0 = blockIdx.x * 16;

  // Wh gates r(0), z(1) -> register fragments (B[k][j]: j=lane&15,
  // k = kt*32 + (lane>>4)*8 + e).  128 VGPRs.
  f16x8 whf[2][2][8];
#pragma unroll
  for (int g = 0; g < 2; ++g)
#pragma unroll
    for (int nt = 0; nt < 2; ++nt) {
      const int col = g * 256 + wave * 32 + nt * 16 + l15;
#pragma unroll
      for (int kt = 0; kt < 8; ++kt)
#pragma unroll
        for (int e = 0; e < 8; ++e)
          whf[g][nt][kt][e] = (f16)Wh[(size_t)(kt * 32 + l4 * 8 + e) * 768 + col];
    }
  // n gate -> LDS fragments (frag-linear: conflict-free b128)
#pragma unroll
  for (int nt = 0; nt < 2; ++nt) {
    const int col = 512 + wave * 32 + nt * 16 + l15;
#pragma unroll
    for (int kt = 0; kt < 8; ++kt) {
      f16x8 v;
#pragma unroll
      for (int e = 0; e < 8; ++e)
        v[e] = (f16)Wh[(size_t)(kt * 32 + l4 * 8 + e) * 768 + col];
      *reinterpret_cast<f16x8*>(reinterpret_cast<char*>(nfr) +
                                ((wave * 2 + nt) * 8 + kt) * 1024 + lane * 16) = v;
    }
  }
  // Wo -> LDS B-frags; wave w writes frame kt=w
  {
    f16x8 v;
#pragma unroll
    for (int e = 0; e < 8; ++e)
      v[e] = (f16)Wo[(wave * 32 + l4 * 8 + e) * 16 + l15];
    *reinterpret_cast<f16x8*>(reinterpret_cast<char*>(wofs) + wave * 1024 +
                              lane * 16) = v;
  }
  float bh[2];
#pragma unroll
  for (int nt = 0; nt < 2; ++nt) bh[nt] = bhn[wave * 32 + nt * 16 + l15];
  const float bov = bo[l15];

  // init h_0: registers (C-layout ownership) + A-frags in buffer 0
  float hcur[2][4];
#pragma unroll
  for (int nt = 0; nt < 2; ++nt) {
    const int s = nt * 2 + (l15 >> 3);
#pragma unroll
    for (int j = 0; j < 4; ++j) {
      const int r = l4 * 4 + j;
      const int c = wave * 32 + nt * 16 + l15;
      float h = carry0[(size_t)(r0 + r) * 256 + c];
      hcur[nt][j] = h;
      const int gl = s * 16 + r;
      const int p = gl ^ (gl >> 3);
      *reinterpret_cast<f16*>(reinterpret_cast<char*>(ha) + wave * 1024 + p * 16 +
                              (l15 & 7) * 2) = (f16)h;
    }
  }
  __syncthreads();

  const f16* gp0 = gxL + ((size_t)blockIdx.x * 8 + wave) * 1536 + lane * 4;
  const int rdoff = (lane ^ (lane >> 3)) * 16;  // swizzled A-frag read offset

  f16x4 gva[6], gvb[6];
#pragma unroll
  for (int i = 0; i < 6; ++i)
    gva[i] = *reinterpret_cast<const f16x4*>(gp0 + i * 256);

  auto step = [&](int cur, int nxt, f16x4 (&gv)[6], f16x4 (&gvn)[6],
                  const f16* gpn, int tt) {
    // prefetch NEXT step's gx (full step of latency cover; stays in flight
    // across the light barrier, waited at next step's first use)
#pragma unroll
    for (int i = 0; i < 6; ++i)
      gvn[i] = *reinterpret_cast<const f16x4*>(gpn + i * 256);

    // C-init: r,z from gx; n from bhn
    f32x4 acc[3][2];
#pragma unroll
    for (int nt = 0; nt < 2; ++nt)
#pragma unroll
      for (int j = 0; j < 4; ++j) {
        acc[0][nt][j] = (float)gv[nt][j];
        acc[1][nt][j] = (float)gv[2 + nt][j];
        acc[2][nt][j] = bh[nt];
      }
#pragma unroll
    for (int kt = 0; kt < 8; ++kt) {
      f16x8 a = *reinterpret_cast<const f16x8*>(
          reinterpret_cast<const char*>(ha) + cur + kt * 1024 + rdoff);
#pragma unroll
      for (int nt = 0; nt < 2; ++nt) {
        f16x8 nb = *reinterpret_cast<const f16x8*>(
            reinterpret_cast<const char*>(nfr) + ((wave * 2 + nt) * 8 + kt) * 1024 +
            lane * 16);
        acc[0][nt] = __builtin_amdgcn_mfma_f32_16x16x32_f16(a, whf[0][nt][kt],
                                                            acc[0][nt], 0, 0, 0);
        acc[1][nt] = __builtin_amdgcn_mfma_f32_16x16x32_f16(a, whf[1][nt][kt],
                                                            acc[1][nt], 0, 0, 0);
        acc[2][nt] = __builtin_amdgcn_mfma_f32_16x16x32_f16(a, nb, acc[2][nt], 0, 0, 0);
      }
    }

    // fused head on wave 0 (overlaps waves 1-7 elementwise)
    if (wave == 0) {
      f32x4 aco = {};
#pragma unroll
      for (int kt = 0; kt < 8; ++kt) {
        f16x8 a = *reinterpret_cast<const f16x8*>(
            reinterpret_cast<const char*>(ha) + cur + kt * 1024 + rdoff);
        f16x8 wb = *reinterpret_cast<const f16x8*>(
            reinterpret_cast<const char*>(wofs) + kt * 1024 + lane * 16);
        aco = __builtin_amdgcn_mfma_f32_16x16x32_f16(a, wb, aco, 0, 0, 0);
      }
      if (tt > 0) {
#pragma unroll
        for (int r = 0; r < 4; ++r) {
          float y = aco[r] + bov;
          if (l15 >= 8) y = __expf(fminf(fmaxf(y, -20.0f), 2.0f));
          out[((size_t)(tt - 1) * 256 + r0 + l4 * 4 + r) * 16 + l15] = y;
        }
      }
    }

    // elementwise GRU + write h_{t+1} A-frags into next buffer
#pragma unroll
    for (int nt = 0; nt < 2; ++nt) {
      const int s = nt * 2 + (l15 >> 3);
#pragma unroll
      for (int j = 0; j < 4; ++j) {
        const int r = l4 * 4 + j;
        float rg = sigm(acc[0][nt][j]);
        float zg = sigm(acc[1][nt][j]);
        float ng = tanh_fast((float)gv[4 + nt][j] + rg * acc[2][nt][j]);
        float h = ng + zg * (hcur[nt][j] - ng);
        hcur[nt][j] = h;
        const int gl = s * 16 + r;
        const int p = gl ^ (gl >> 3);
        *reinterpret_cast<f16*>(reinterpret_cast<char*>(ha) + nxt + wave * 1024 +
                                p * 16 + (l15 & 7) * 2) = (f16)h;
      }
    }
    // lightweight barrier: order LDS h-handoff only (no vmcnt drain)
    asm volatile("s_waitcnt lgkmcnt(0)\n\ts_barrier" ::: "memory");
  };

  for (int t = 0; t < 512; t += 2) {
    const f16* gp1 = gp0 + (size_t)(t + 1) * 196608;
    const f16* gp2 = gp0 + (size_t)(t + 2 <= 511 ? t + 2 : 511) * 196608;
    step(0, 8192, gva, gvb, gp1, t);
    step(8192, 0, gvb, gva, gp2, t + 1);
  }

  // final head: out[511] = h_512 @ Wo  (h_512 lives in buffer 0)
  if (wave == 0) {
    f32x4 aco = {};
#pragma unroll
    for (int kt = 0; kt < 8; ++kt) {
      f16x8 a = *reinterpret_cast<const f16x8*>(
          reinterpret_cast<const char*>(ha) + kt * 1024 + rdoff);
      f16x8 wb = *reinterpret_cast<const f16x8*>(
          reinterpret_cast<const char*>(wofs) + kt * 1024 + lane * 16);
      aco = __builtin_amdgcn_mfma_f32_16x16x32_f16(a, wb, aco, 0, 0, 0);
    }
#pragma unroll
    for (int r = 0; r < 4; ++r) {
      float y = aco[r] + bov;
      if (l15 >= 8) y = __expf(fminf(fmaxf(y, -20.0f), 2.0f));
      out[((size_t)511 * 256 + r0 + l4 * 4 + r) * 16 + l15] = y;
    }
  }
}

extern "C" void kernel_launch(void* const* d_in, const int* in_sizes, int n_in,
                              void* d_out, int out_size, void* d_ws, size_t ws_size,
                              hipStream_t stream) {
  const float* x      = (const float*)d_in[0];
  const float* carry0 = (const float*)d_in[1];
  const float* Wi     = (const float*)d_in[2];
  const float* bi     = (const float*)d_in[3];
  const float* Wh     = (const float*)d_in[4];
  const float* bhn    = (const float*)d_in[5];
  const float* Wo     = (const float*)d_in[6];
  const float* bo     = (const float*)d_in[7];
  float* out = (float*)d_out;

  f16* gx  = (f16*)d_ws;                       // 512*256*768 f16 = 192 MiB
  f16* WiT = gx + (size_t)512 * 256 * 768;     // 768*256 f16

  k_prep_wit<<<dim3(768), dim3(256), 0, stream>>>(Wi, WiT);
  k_gemm_gx<<<dim3(6, 1024), dim3(256), 0, stream>>>(x, WiT, bi, gx);
  k_scan<<<dim3(16), dim3(512), 0, stream>>>(carry0, Wh, bhn, gx, Wo, bo, out);
}